// Round 8
// baseline (414.375 us; speedup 1.0000x reference)
//
#include <hip/hip_runtime.h>

typedef unsigned short u16;
typedef __attribute__((ext_vector_type(8))) short bf16x8;
typedef __attribute__((ext_vector_type(8))) unsigned short u16x8;
typedef __attribute__((ext_vector_type(4))) float f32x4;

#define L_SEQ 2048
#define NTOK 4096   // B*L
#define DMODEL 1024
#define DEXP 2048
#define NH 16
#define DH 128

__device__ __forceinline__ u16 f2bf(float f) {
    unsigned u = __float_as_uint(f);
    unsigned r = (u + 0x7FFFu + ((u >> 16) & 1u)) >> 16;
    return (u16)r;
}
__device__ __forceinline__ float bf2f(u16 h) {
    return __uint_as_float(((unsigned)h) << 16);
}

// DPP cross-lane (16-lane row) reduction helpers: VALU latency, no LDS.
template <int CTRL>
__device__ __forceinline__ float dpp_f(float x) {
    return __int_as_float(__builtin_amdgcn_update_dpp(0, __float_as_int(x), CTRL, 0xF, 0xF, true));
}
__device__ __forceinline__ float red16_max(float x) {
    x = fmaxf(x, dpp_f<0xB1>(x));   // quad_perm xor1
    x = fmaxf(x, dpp_f<0x4E>(x));   // quad_perm xor2
    x = fmaxf(x, dpp_f<0x124>(x));  // row_ror:4
    x = fmaxf(x, dpp_f<0x128>(x));  // row_ror:8
    return x;
}

// async global->LDS, 16B per lane; LDS dest = wave-uniform base + lane*16
__device__ __forceinline__ void gl_lds16(const u16* g, u16* l) {
    __builtin_amdgcn_global_load_lds((const __attribute__((address_space(1))) void*)g,
                                     (__attribute__((address_space(3))) void*)l, 16, 0, 0);
}

// ---------------- convert + transpose fp32 -> bf16, out[c*R + r] = in[r*C + c]
__global__ void conv_transpose(const float* __restrict__ in, u16* __restrict__ out, int R, int C) {
    __shared__ unsigned tile[32][33];
    int c0 = blockIdx.x * 32, r0 = blockIdx.y * 32;
    int tx = threadIdx.x, ty = threadIdx.y;
    for (int j = 0; j < 32; j += 8)
        tile[ty + j][tx] = (unsigned)f2bf(in[(size_t)(r0 + ty + j) * C + c0 + tx]);
    __syncthreads();
    for (int j = 0; j < 32; j += 8)
        out[(size_t)(c0 + ty + j) * R + r0 + tx] = (u16)tile[tx][ty + j];
}

// ---------------- layernorm over 1024, out bf16 or fp32
__global__ __launch_bounds__(256) void ln_fwd(const float* __restrict__ x, const float* __restrict__ g,
                                              const float* __restrict__ bta, void* __restrict__ outp,
                                              int out_bf16) {
    int row = blockIdx.x;
    int t = threadIdx.x;
    const float* xr = x + (size_t)row * DMODEL;
    float4 xv = *(const float4*)&xr[t * 4];
    float s = xv.x + xv.y + xv.z + xv.w;
    float s2 = xv.x * xv.x + xv.y * xv.y + xv.z * xv.z + xv.w * xv.w;
    for (int off = 32; off >= 1; off >>= 1) {
        s += __shfl_xor(s, off);
        s2 += __shfl_xor(s2, off);
    }
    __shared__ float red[10];
    int w = t >> 6;
    if ((t & 63) == 0) { red[w] = s; red[4 + w] = s2; }
    __syncthreads();
    if (t == 0) {
        red[8] = red[0] + red[1] + red[2] + red[3];
        red[9] = red[4] + red[5] + red[6] + red[7];
    }
    __syncthreads();
    float mu = red[8] * (1.0f / DMODEL);
    float var = red[9] * (1.0f / DMODEL) - mu * mu;
    float rstd = rsqrtf(var + 1e-5f);
    float vals[4] = {xv.x, xv.y, xv.z, xv.w};
    for (int e = 0; e < 4; e++) {
        int c = t * 4 + e;
        float y = (vals[e] - mu) * rstd * g[c] + bta[c];
        if (out_bf16) ((u16*)outp)[(size_t)row * DMODEL + c] = f2bf(y);
        else          ((float*)outp)[(size_t)row * DMODEL + c] = y;
    }
}

// ---------------- GEMM: C[M,N] = A[M,K](bf16) * B[K,N], B given as BT[N,K] bf16
__device__ __forceinline__ void store_out(u16* C, size_t idx, float v) { C[idx] = f2bf(v); }
__device__ __forceinline__ void store_out(float* C, size_t idx, float v) { C[idx] = v; }

template <typename OutT>
__global__ __launch_bounds__(256) void gemm_bt(const u16* __restrict__ A, const u16* __restrict__ BT,
                                               OutT* __restrict__ C, int M, int N, int K) {
    __shared__ u16 a_s[4096];   // 128 rows x 32 k, chunked: chunk c = rows 16c..16c+15
    __shared__ u16 b_s[4096];
    int tid = threadIdx.x;
    int m0 = blockIdx.y * 128, n0 = blockIdx.x * 128;
    int w = tid >> 6, lane = tid & 63, quad = lane >> 4, ln = lane & 15;
    int wr = (w >> 1) * 64, wc = (w & 1) * 64;
    f32x4 zero4 = {0.f, 0.f, 0.f, 0.f};
    f32x4 acc[4][4];
    for (int r = 0; r < 4; r++)
        for (int c = 0; c < 4; c++) acc[r][c] = zero4;

    int lrow = lane >> 2, lseg = (lane & 3) * 8;
    const u16* Ag0 = A + (size_t)(m0 + 32 * w + lrow) * K + lseg;
    const u16* Ag1 = Ag0 + (size_t)16 * K;
    const u16* Bg0 = BT + (size_t)(n0 + 32 * w + lrow) * K + lseg;
    const u16* Bg1 = Bg0 + (size_t)16 * K;
    u16* al0 = &a_s[(2 * w) * 512];
    u16* al1 = &a_s[(2 * w + 1) * 512];
    u16* bl0 = &b_s[(2 * w) * 512];
    u16* bl1 = &b_s[(2 * w + 1) * 512];

    for (int k0 = 0; k0 < K; k0 += 32) {
        __syncthreads();
        gl_lds16(Ag0 + k0, al0);
        gl_lds16(Ag1 + k0, al1);
        gl_lds16(Bg0 + k0, bl0);
        gl_lds16(Bg1 + k0, bl1);
        __syncthreads();
        bf16x8 af[4], bfr[4];
        for (int r = 0; r < 4; r++) af[r]  = *(const bf16x8*)&a_s[(wr + r * 16 + ln) * 32 + quad * 8];
        for (int c = 0; c < 4; c++) bfr[c] = *(const bf16x8*)&b_s[(wc + c * 16 + ln) * 32 + quad * 8];
        for (int r = 0; r < 4; r++)
            for (int c = 0; c < 4; c++)
                acc[r][c] = __builtin_amdgcn_mfma_f32_16x16x32_bf16(af[r], bfr[c], acc[r][c], 0, 0, 0);
    }
    for (int r = 0; r < 4; r++)
        for (int c = 0; c < 4; c++)
            for (int e = 0; e < 4; e++) {
                int row = m0 + wr + r * 16 + quad * 4 + e;
                int col = n0 + wc + c * 16 + ln;
                store_out(C, (size_t)row * N + col, acc[r][c][e]);
            }
}

// ---------------- smear: k_sm[bh][l][d] = (1-s)*k + s*k_prev  (head-major layout)
__global__ __launch_bounds__(256) void smear_kernel(const u16* __restrict__ qkvp,
                                                    const float* __restrict__ smear_f,
                                                    u16* __restrict__ k_sm) {
    int gid = blockIdx.x * 256 + threadIdx.x;
    int base = gid * 8;
    int bl = base >> 11;       // token index
    int c = base & 2047;
    int h = c >> 7;
    int d = c & 127;
    int l = bl & (L_SEQ - 1);
    int bb = bl >> 11;
    float s = 1.0f / (1.0f + __expf(-smear_f[h]));
    u16x8 cur = *(const u16x8*)&qkvp[(size_t)bl * 8192 + 2048 + c];
    u16x8 prv = {0, 0, 0, 0, 0, 0, 0, 0};
    if (l > 0) prv = *(const u16x8*)&qkvp[(size_t)(bl - 1) * 8192 + 2048 + c];
    u16x8 outv;
    for (int u = 0; u < 8; u++) {
        float kc = bf2f(cur[u]);
        float kp = bf2f(prv[u]);
        outv[u] = f2bf((1.0f - s) * kc + s * kp);
    }
    *(u16x8*)&k_sm[(((size_t)(bb * 16 + h)) * L_SEQ + l) * DH + d] = outv;
}

// ---------------- per-(b,h) transpose of V: v_t[bh,d,l] = qkvp[tok, 4096 + h*128 + d]
__global__ void vT_kernel(const u16* __restrict__ qkvp, u16* __restrict__ v_t) {
    __shared__ unsigned tile[32][33];
    int l0 = blockIdx.x * 32, d0 = blockIdx.y * 32;
    int bh = blockIdx.z;
    int bb = bh >> 4, h = bh & 15;
    int tx = threadIdx.x, ty = threadIdx.y;
    size_t tokb = (size_t)bb * L_SEQ;
    for (int j = 0; j < 32; j += 8)
        tile[ty + j][tx] = (unsigned)qkvp[(tokb + l0 + ty + j) * 8192 + 4096 + h * DH + d0 + tx];
    __syncthreads();
    for (int j = 0; j < 32; j += 8)
        v_t[((size_t)bh * DH + d0 + ty + j) * L_SEQ + l0 + tx] = (u16)tile[tx][ty + j];
}

// ---------------- flash attention + SiLU(p) gating
// Balanced + double-buffered: grid (8, 32). Block bx does strips (15-bx) then (bx),
// flattened into 36 j-iterations total (identical for every block; 1 block/CU).
// Wave = 32 rows (2 x 16 mt). j-tile 64. K/V double-buffered; 1 barrier per iter;
// next tile's global_load_lds issued right after the barrier, overlapping compute.
// K LDS: 2 x [kt 0..3][jrow 0..63][32 k] = 32 KB
// V LDS: 2 x [jt 0..1][d 0..127][32 j]   = 32 KB
// P LDS: per-wave 32 x 72                = 18 KB   (total 82 KB, 1 block/CU)
__global__ __launch_bounds__(256, 2) void attn_kernel(const u16* __restrict__ qkvp,
                                                      const u16* __restrict__ k_sm,
                                                      const u16* __restrict__ v_t,
                                                      u16* __restrict__ ag2,
                                                      const float* __restrict__ log_scale) {
    __shared__ u16 k_s[2][8192];
    __shared__ u16 vt_s[2][8192];
    __shared__ u16 p_s[9216];
    int tid = threadIdx.x;
    int bx = blockIdx.x;          // 0..7
    int bh = blockIdx.y;
    int bb = bh >> 4, h = bh & 15;
    int w = tid >> 6, lane = tid & 63, quad = lane >> 4, ln = lane & 15;
    size_t tokb = (size_t)bb * L_SEQ;

    const float LOG2E = 1.44269504f;
    float inv = 1.0f / (__expf(2.0f * log_scale[h]) * sqrtf((float)DH));
    float scl = inv * LOG2E;
    float slope2 = ((h < 8) ? exp2f(-8.0f * (float)h / 7.0f) : 0.0f) * LOG2E;

    const int ibA = 15 - bx, ibB = bx;
    const int nA = 2 * ibA + 2, nB = 2 * ibB + 2;
    const int ntot = nA + nB;     // 36 for every block

    int lrow = lane >> 2, lseg8 = (lane & 3) * 8;
    const u16* kbase = k_sm + (size_t)bh * L_SEQ * DH + w * 32 + lseg8;
    const u16* vbase = v_t + (size_t)bh * DH * L_SEQ + lseg8;

    u16* pw = &p_s[w * 2304];
    const short ONE_BF = (short)0x3F80;
    bf16x8 ones = {ONE_BF, ONE_BF, ONE_BF, ONE_BF, ONE_BF, ONE_BF, ONE_BF, ONE_BF};
    f32x4 zero4 = {0.f, 0.f, 0.f, 0.f};

    auto stage = [&](int t) {
        int b = t & 1;
        int j0 = (t < nA ? t : t - nA) * 64;
        for (int g = 0; g < 4; g++)
            gl_lds16(kbase + (size_t)(j0 + g * 16 + lrow) * DH, &k_s[b][w * 2048 + g * 512]);
        for (int q = 0; q < 4; q++) {
            int c = w * 4 + q;
            int jt = c >> 3, dg = c & 7;
            gl_lds16(vbase + (size_t)(dg * 16 + lrow) * L_SEQ + jt * 32 + j0,
                     &vt_s[b][jt * 4096 + dg * 512]);
        }
    };

    int i0 = ibA * 128;
    int si = i0 + w * 32;

    bf16x8 qf[2][4];
    auto load_q = [&]() {
        for (int mt = 0; mt < 2; mt++)
            for (int kt = 0; kt < 4; kt++)
                qf[mt][kt] = *(const bf16x8*)&qkvp[(tokb + si + mt * 16 + ln) * 8192 + h * DH + kt * 32 + quad * 8];
    };
    load_q();

    float m_i[2][4];
    f32x4 o_acc[2][8], l_acc[2];
    auto reset_state = [&]() {
        for (int mt = 0; mt < 2; mt++) {
            for (int r = 0; r < 4; r++) m_i[mt][r] = -1e30f;
            for (int dt = 0; dt < 8; dt++) o_acc[mt][dt] = zero4;
            l_acc[mt] = zero4;
        }
    };
    reset_state();

    auto epilogue = [&]() {
        for (int mt = 0; mt < 2; mt++) {
            float rinv[4];
            for (int r = 0; r < 4; r++) rinv[r] = __builtin_amdgcn_rcpf(l_acc[mt][r]);
            for (int dt = 0; dt < 8; dt++)
                for (int r = 0; r < 4; r++) {
                    int i = si + mt * 16 + quad * 4 + r;
                    int dcol = dt * 16 + ln;
                    float o = o_acc[mt][dt][r] * rinv[r];
                    float pv = bf2f(qkvp[(tokb + i) * 8192 + 6144 + h * DH + dcol]);
                    float gate = pv * __builtin_amdgcn_rcpf(1.0f + exp2f(-pv * LOG2E));
                    ag2[(tokb + i) * 2048 + h * DH + dcol] = f2bf(gate * o);
                }
        }
    };

    stage(0);

    for (int t = 0; t < ntot; t++) {
        int b = t & 1;
        int j0 = (t < nA ? t : t - nA) * 64;
        __syncthreads();               // compiler emits vmcnt(0) drain: buf b staged
        if (t + 1 < ntot) stage(t + 1);  // prefetch into other buffer, overlaps compute

        if (j0 <= si + 31) {
            // S = Q K^T: 32 rows x 64 cols per wave (B-frags shared across mt)
            f32x4 sc[2][4];
            for (int mt = 0; mt < 2; mt++)
                for (int ct = 0; ct < 4; ct++) sc[mt][ct] = zero4;
            for (int kt = 0; kt < 4; kt++)
                for (int ct = 0; ct < 4; ct++) {
                    bf16x8 bfr = *(const bf16x8*)&k_s[b][kt * 2048 + (ct * 16 + ln) * 32 + quad * 8];
                    sc[0][ct] = __builtin_amdgcn_mfma_f32_16x16x32_bf16(qf[0][kt], bfr, sc[0][ct], 0, 0, 0);
                    sc[1][ct] = __builtin_amdgcn_mfma_f32_16x16x32_bf16(qf[1][kt], bfr, sc[1][ct], 0, 0, 0);
                }

            float alpha[2][4];
            bool any_resc = false;
            float aj0 = slope2 * (float)(j0 + ln);
            for (int mt = 0; mt < 2; mt++) {
                int smt = si + mt * 16;
                bool full = (j0 + 63 <= smt);
                float s2[4][4];
                for (int ct = 0; ct < 4; ct++) {
                    float ajv = aj0 + slope2 * (float)(16 * ct);
                    int j = j0 + ct * 16 + ln;
                    for (int r = 0; r < 4; r++) {
                        float v = fmaf(sc[mt][ct][r], scl, ajv);
                        if (!full) {
                            int i = smt + quad * 4 + r;
                            if (j > i) v = -3.0e38f;
                        }
                        s2[ct][r] = v;
                    }
                }
                for (int r = 0; r < 4; r++) {
                    float mr = fmaxf(fmaxf(s2[0][r], s2[1][r]), fmaxf(s2[2][r], s2[3][r]));
                    mr = red16_max(mr);
                    float mnew = fmaxf(m_i[mt][r], mr);
                    alpha[mt][r] = exp2f(m_i[mt][r] - mnew);
                    any_resc |= (alpha[mt][r] != 1.0f);
                    m_i[mt][r] = mnew;
                    for (int ct = 0; ct < 4; ct++) {
                        float p = exp2f(s2[ct][r] - mnew);
                        u16 pb = (u16)(__float_as_uint(p) >> 16);  // trunc; consistent num/denom
                        pw[(mt * 16 + quad * 4 + r) * 72 + ct * 16 + ln] = pb;
                    }
                }
            }
            if (__any(any_resc)) {
                for (int mt = 0; mt < 2; mt++) {
                    for (int dt = 0; dt < 8; dt++) {
                        f32x4 o = o_acc[mt][dt];
                        for (int r = 0; r < 4; r++) o[r] *= alpha[mt][r];
                        o_acc[mt][dt] = o;
                    }
                    f32x4 lv = l_acc[mt];
                    for (int r = 0; r < 4; r++) lv[r] *= alpha[mt][r];
                    l_acc[mt] = lv;
                }
            }
            asm volatile("s_waitcnt lgkmcnt(0)" ::: "memory");
            for (int ks = 0; ks < 2; ks++) {
                bf16x8 pa0 = *(const bf16x8*)&pw[ln * 72 + ks * 32 + quad * 8];
                bf16x8 pa1 = *(const bf16x8*)&pw[(16 + ln) * 72 + ks * 32 + quad * 8];
                l_acc[0] = __builtin_amdgcn_mfma_f32_16x16x32_bf16(pa0, ones, l_acc[0], 0, 0, 0);
                l_acc[1] = __builtin_amdgcn_mfma_f32_16x16x32_bf16(pa1, ones, l_acc[1], 0, 0, 0);
                for (int dt = 0; dt < 8; dt++) {
                    bf16x8 vf = *(const bf16x8*)&vt_s[b][ks * 4096 + (dt * 16 + ln) * 32 + quad * 8];
                    o_acc[0][dt] = __builtin_amdgcn_mfma_f32_16x16x32_bf16(pa0, vf, o_acc[0][dt], 0, 0, 0);
                    o_acc[1][dt] = __builtin_amdgcn_mfma_f32_16x16x32_bf16(pa1, vf, o_acc[1][dt], 0, 0, 0);
                }
            }
        }

        if (t == nA - 1) {   // strip A finished: write it out, switch to strip B
            epilogue();
            i0 = ibB * 128;
            si = i0 + w * 32;
            load_q();
            reset_state();
        }
    }
    epilogue();
}

extern "C" void kernel_launch(void* const* d_in, const int* in_sizes, int n_in,
                              void* d_out, int out_size, void* d_ws, size_t ws_size,
                              hipStream_t stream) {
    const float* x       = (const float*)d_in[0];
    const float* ln1_g   = (const float*)d_in[1];
    const float* ln1_b   = (const float*)d_in[2];
    const float* ln2_g   = (const float*)d_in[3];
    const float* ln2_b   = (const float*)d_in[4];
    const float* w_in    = (const float*)d_in[5];
    const float* w_out   = (const float*)d_in[6];
    const float* smear_f = (const float*)d_in[7];
    const float* logsc   = (const float*)d_in[8];
    float* out = (float*)d_out;
    char* ws = (char*)d_ws;

    // ws layout (bytes)
    u16* w_inT   = (u16*)(ws + 0);                       // 16 MB  [8192,1024]
    u16* w_outT  = (u16*)(ws + (size_t)16777216);        //  4 MB  [1024,2048]
    u16* lnA     = (u16*)(ws + (size_t)20971520);        //  8 MB  [4096,1024]
    u16* qkvp    = (u16*)(ws + (size_t)29360128);        // 64 MB  [4096,8192]
    u16* k_sm    = (u16*)(ws + (size_t)96468992);        // 16 MB  [bh][l][128]
    u16* ag2     = (u16*)(ws + (size_t)113246208);       // 16 MB  [4096,2048]
    float* out_pre = (float*)(ws + (size_t)96468992);    // alias k_sm (dead after attn)
    u16* v_t     = (u16*)(ws + 0);                       // alias w_inT (dead after gemm1)

    dim3 b32x8(32, 8);
    conv_transpose<<<dim3(8192 / 32, 1024 / 32), b32x8, 0, stream>>>(w_in, w_inT, 1024, 8192);
    conv_transpose<<<dim3(1024 / 32, 2048 / 32), b32x8, 0, stream>>>(w_out, w_outT, 2048, 1024);
    ln_fwd<<<NTOK, 256, 0, stream>>>(x, ln1_g, ln1_b, (void*)lnA, 1);
    gemm_bt<u16><<<dim3(8192 / 128, 4096 / 128), 256, 0, stream>>>(lnA, w_inT, qkvp, NTOK, 8192, 1024);
    smear_kernel<<<4096, 256, 0, stream>>>(qkvp, smear_f, k_sm);
    vT_kernel<<<dim3(L_SEQ / 32, DH / 32, 32), b32x8, 0, stream>>>(qkvp, v_t);
    attn_kernel<<<dim3(8, 32), 256, 0, stream>>>(qkvp, k_sm, v_t, ag2, logsc);
    gemm_bt<float><<<dim3(1024 / 128, 4096 / 128), 256, 0, stream>>>(ag2, w_outT, out_pre, NTOK, 1024, 2048);
    ln_fwd<<<NTOK, 256, 0, stream>>>(out_pre, ln2_g, ln2_b, (void*)out, 0);
}

// Round 9
// 383.851 us; speedup vs baseline: 1.0795x; 1.0795x over previous
//
#include <hip/hip_runtime.h>

typedef unsigned short u16;
typedef __attribute__((ext_vector_type(8))) short bf16x8;
typedef __attribute__((ext_vector_type(8))) unsigned short u16x8;
typedef __attribute__((ext_vector_type(4))) float f32x4;

#define L_SEQ 2048
#define NTOK 4096   // B*L
#define DMODEL 1024
#define DEXP 2048
#define NH 16
#define DH 128

__device__ __forceinline__ u16 f2bf(float f) {
    unsigned u = __float_as_uint(f);
    unsigned r = (u + 0x7FFFu + ((u >> 16) & 1u)) >> 16;
    return (u16)r;
}
__device__ __forceinline__ float bf2f(u16 h) {
    return __uint_as_float(((unsigned)h) << 16);
}

// DPP cross-lane (16-lane row) reduction helpers: VALU latency, no LDS.
template <int CTRL>
__device__ __forceinline__ float dpp_f(float x) {
    return __int_as_float(__builtin_amdgcn_update_dpp(0, __float_as_int(x), CTRL, 0xF, 0xF, true));
}
__device__ __forceinline__ float red16_max(float x) {
    x = fmaxf(x, dpp_f<0xB1>(x));   // quad_perm xor1
    x = fmaxf(x, dpp_f<0x4E>(x));   // quad_perm xor2
    x = fmaxf(x, dpp_f<0x124>(x));  // row_ror:4
    x = fmaxf(x, dpp_f<0x128>(x));  // row_ror:8
    return x;
}

// async global->LDS, 16B per lane; LDS dest = wave-uniform base + lane*16
__device__ __forceinline__ void gl_lds16(const u16* g, u16* l) {
    __builtin_amdgcn_global_load_lds((const __attribute__((address_space(1))) void*)g,
                                     (__attribute__((address_space(3))) void*)l, 16, 0, 0);
}

// ---------------- convert + transpose fp32 -> bf16, out[c*R + r] = in[r*C + c]
__global__ void conv_transpose(const float* __restrict__ in, u16* __restrict__ out, int R, int C) {
    __shared__ unsigned tile[32][33];
    int c0 = blockIdx.x * 32, r0 = blockIdx.y * 32;
    int tx = threadIdx.x, ty = threadIdx.y;
    for (int j = 0; j < 32; j += 8)
        tile[ty + j][tx] = (unsigned)f2bf(in[(size_t)(r0 + ty + j) * C + c0 + tx]);
    __syncthreads();
    for (int j = 0; j < 32; j += 8)
        out[(size_t)(c0 + ty + j) * R + r0 + tx] = (u16)tile[tx][ty + j];
}

// ---------------- layernorm over 1024, out bf16 or fp32
__global__ __launch_bounds__(256) void ln_fwd(const float* __restrict__ x, const float* __restrict__ g,
                                              const float* __restrict__ bta, void* __restrict__ outp,
                                              int out_bf16) {
    int row = blockIdx.x;
    int t = threadIdx.x;
    const float* xr = x + (size_t)row * DMODEL;
    float4 xv = *(const float4*)&xr[t * 4];
    float s = xv.x + xv.y + xv.z + xv.w;
    float s2 = xv.x * xv.x + xv.y * xv.y + xv.z * xv.z + xv.w * xv.w;
    for (int off = 32; off >= 1; off >>= 1) {
        s += __shfl_xor(s, off);
        s2 += __shfl_xor(s2, off);
    }
    __shared__ float red[10];
    int w = t >> 6;
    if ((t & 63) == 0) { red[w] = s; red[4 + w] = s2; }
    __syncthreads();
    if (t == 0) {
        red[8] = red[0] + red[1] + red[2] + red[3];
        red[9] = red[4] + red[5] + red[6] + red[7];
    }
    __syncthreads();
    float mu = red[8] * (1.0f / DMODEL);
    float var = red[9] * (1.0f / DMODEL) - mu * mu;
    float rstd = rsqrtf(var + 1e-5f);
    float vals[4] = {xv.x, xv.y, xv.z, xv.w};
    for (int e = 0; e < 4; e++) {
        int c = t * 4 + e;
        float y = (vals[e] - mu) * rstd * g[c] + bta[c];
        if (out_bf16) ((u16*)outp)[(size_t)row * DMODEL + c] = f2bf(y);
        else          ((float*)outp)[(size_t)row * DMODEL + c] = y;
    }
}

// ---------------- GEMM: C[M,N] = A[M,K](bf16) * B[K,N], B given as BT[N,K] bf16
__device__ __forceinline__ void store_out(u16* C, size_t idx, float v) { C[idx] = f2bf(v); }
__device__ __forceinline__ void store_out(float* C, size_t idx, float v) { C[idx] = v; }

template <typename OutT>
__global__ __launch_bounds__(256) void gemm_bt(const u16* __restrict__ A, const u16* __restrict__ BT,
                                               OutT* __restrict__ C, int M, int N, int K) {
    __shared__ u16 a_s[4096];   // 128 rows x 32 k, chunked: chunk c = rows 16c..16c+15
    __shared__ u16 b_s[4096];
    int tid = threadIdx.x;
    int m0 = blockIdx.y * 128, n0 = blockIdx.x * 128;
    int w = tid >> 6, lane = tid & 63, quad = lane >> 4, ln = lane & 15;
    int wr = (w >> 1) * 64, wc = (w & 1) * 64;
    f32x4 zero4 = {0.f, 0.f, 0.f, 0.f};
    f32x4 acc[4][4];
    for (int r = 0; r < 4; r++)
        for (int c = 0; c < 4; c++) acc[r][c] = zero4;

    int lrow = lane >> 2, lseg = (lane & 3) * 8;
    const u16* Ag0 = A + (size_t)(m0 + 32 * w + lrow) * K + lseg;
    const u16* Ag1 = Ag0 + (size_t)16 * K;
    const u16* Bg0 = BT + (size_t)(n0 + 32 * w + lrow) * K + lseg;
    const u16* Bg1 = Bg0 + (size_t)16 * K;
    u16* al0 = &a_s[(2 * w) * 512];
    u16* al1 = &a_s[(2 * w + 1) * 512];
    u16* bl0 = &b_s[(2 * w) * 512];
    u16* bl1 = &b_s[(2 * w + 1) * 512];

    for (int k0 = 0; k0 < K; k0 += 32) {
        __syncthreads();
        gl_lds16(Ag0 + k0, al0);
        gl_lds16(Ag1 + k0, al1);
        gl_lds16(Bg0 + k0, bl0);
        gl_lds16(Bg1 + k0, bl1);
        __syncthreads();
        bf16x8 af[4], bfr[4];
        for (int r = 0; r < 4; r++) af[r]  = *(const bf16x8*)&a_s[(wr + r * 16 + ln) * 32 + quad * 8];
        for (int c = 0; c < 4; c++) bfr[c] = *(const bf16x8*)&b_s[(wc + c * 16 + ln) * 32 + quad * 8];
        for (int r = 0; r < 4; r++)
            for (int c = 0; c < 4; c++)
                acc[r][c] = __builtin_amdgcn_mfma_f32_16x16x32_bf16(af[r], bfr[c], acc[r][c], 0, 0, 0);
    }
    for (int r = 0; r < 4; r++)
        for (int c = 0; c < 4; c++)
            for (int e = 0; e < 4; e++) {
                int row = m0 + wr + r * 16 + quad * 4 + e;
                int col = n0 + wc + c * 16 + ln;
                store_out(C, (size_t)row * N + col, acc[r][c][e]);
            }
}

// ---------------- smear: k_sm[bh][l][d] = (1-s)*k + s*k_prev  (head-major layout)
__global__ __launch_bounds__(256) void smear_kernel(const u16* __restrict__ qkvp,
                                                    const float* __restrict__ smear_f,
                                                    u16* __restrict__ k_sm) {
    int gid = blockIdx.x * 256 + threadIdx.x;
    int base = gid * 8;
    int bl = base >> 11;       // token index
    int c = base & 2047;
    int h = c >> 7;
    int d = c & 127;
    int l = bl & (L_SEQ - 1);
    int bb = bl >> 11;
    float s = 1.0f / (1.0f + __expf(-smear_f[h]));
    u16x8 cur = *(const u16x8*)&qkvp[(size_t)bl * 8192 + 2048 + c];
    u16x8 prv = {0, 0, 0, 0, 0, 0, 0, 0};
    if (l > 0) prv = *(const u16x8*)&qkvp[(size_t)(bl - 1) * 8192 + 2048 + c];
    u16x8 outv;
    for (int u = 0; u < 8; u++) {
        float kc = bf2f(cur[u]);
        float kp = bf2f(prv[u]);
        outv[u] = f2bf((1.0f - s) * kc + s * kp);
    }
    *(u16x8*)&k_sm[(((size_t)(bb * 16 + h)) * L_SEQ + l) * DH + d] = outv;
}

// ---------------- per-(b,h) transpose of V: v_t[bh,d,l] = qkvp[tok, 4096 + h*128 + d]
__global__ void vT_kernel(const u16* __restrict__ qkvp, u16* __restrict__ v_t) {
    __shared__ unsigned tile[32][33];
    int l0 = blockIdx.x * 32, d0 = blockIdx.y * 32;
    int bh = blockIdx.z;
    int bb = bh >> 4, h = bh & 15;
    int tx = threadIdx.x, ty = threadIdx.y;
    size_t tokb = (size_t)bb * L_SEQ;
    for (int j = 0; j < 32; j += 8)
        tile[ty + j][tx] = (unsigned)qkvp[(tokb + l0 + ty + j) * 8192 + 4096 + h * DH + d0 + tx];
    __syncthreads();
    for (int j = 0; j < 32; j += 8)
        v_t[((size_t)bh * DH + d0 + ty + j) * L_SEQ + l0 + tx] = (u16)tile[tx][ty + j];
}

// ---------------- flash attention + SiLU(p) gating
// Round-6 schedule + round-7 softmax: grid (16,32), block bx does strips (31-bx)
// then (bx) => 33 j-iters for every block; 42 KB LDS => 2 blocks/CU co-resident.
// Wave = 16 rows (Q in regs), j-tile 64. l via MFMA ones-B-frag; lazy rescale.
// K LDS: [kt 0..3][jrow 0..63][32 k] = 8192 u16 (16 KB)
// V LDS: [jt 0..1][d 0..127][32 j]   = 8192 u16 (16 KB)
// P LDS: per-wave 16 x 72            = 4608 u16 ( 9 KB)
__global__ __launch_bounds__(256) void attn_kernel(const u16* __restrict__ qkvp,
                                                   const u16* __restrict__ k_sm,
                                                   const u16* __restrict__ v_t,
                                                   u16* __restrict__ ag2,
                                                   const float* __restrict__ log_scale) {
    __shared__ u16 k_s[8192];
    __shared__ u16 vt_s[8192];
    __shared__ u16 p_s[4608];
    int tid = threadIdx.x;
    int bh = blockIdx.y;
    int bb = bh >> 4, h = bh & 15;
    int w = tid >> 6, lane = tid & 63, quad = lane >> 4, ln = lane & 15;
    size_t tokb = (size_t)bb * L_SEQ;

    const float LOG2E = 1.44269504f;
    float inv = 1.0f / (__expf(2.0f * log_scale[h]) * sqrtf((float)DH));
    float scl = inv * LOG2E;
    float slope2 = ((h < 8) ? exp2f(-8.0f * (float)h / 7.0f) : 0.0f) * LOG2E;

    int lrow = lane >> 2, lseg8 = (lane & 3) * 8;
    f32x4 zero4 = {0.f, 0.f, 0.f, 0.f};
    u16* pw = &p_s[w * 1152];
    const short ONE_BF = (short)0x3F80;
    bf16x8 ones = {ONE_BF, ONE_BF, ONE_BF, ONE_BF, ONE_BF, ONE_BF, ONE_BF, ONE_BF};

    for (int sidx = 0; sidx < 2; sidx++) {
        int ib = sidx == 0 ? (31 - (int)blockIdx.x) : (int)blockIdx.x;
        int i0 = ib * 64;
        int si = i0 + w * 16;

        // Q fragments straight from global (A-layout: m=ln, k=quad*8+..)
        bf16x8 qf[4];
        for (int kt = 0; kt < 4; kt++)
            qf[kt] = *(const bf16x8*)&qkvp[(tokb + si + ln) * 8192 + h * DH + kt * 32 + quad * 8];

        float m_i[4];
        for (int r = 0; r < 4; r++) m_i[r] = -1e30f;
        f32x4 o_acc[8], l_acc;
        for (int dt = 0; dt < 8; dt++) o_acc[dt] = zero4;
        l_acc = zero4;

        // staging pointers: advance by constant per j-tile
        const u16* kg[4];
        for (int g = 0; g < 4; g++)
            kg[g] = k_sm + ((size_t)bh * L_SEQ + g * 16 + lrow) * DH + w * 32 + lseg8;
        const u16* vg[4];
        u16* vl[4];
        for (int q = 0; q < 4; q++) {
            int c = w * 4 + q;
            int jt = c >> 3, dg = c & 7;
            vg[q] = v_t + ((size_t)bh * DH + dg * 16 + lrow) * L_SEQ + jt * 32 + lseg8;
            vl[q] = &vt_s[jt * 4096 + dg * 512];
        }

        for (int j0 = 0; j0 <= i0; j0 += 64) {
            __syncthreads();
            for (int g = 0; g < 4; g++) {
                gl_lds16(kg[g], &k_s[w * 2048 + g * 512]);
                kg[g] += 64 * DH;
            }
            for (int q = 0; q < 4; q++) {
                gl_lds16(vg[q], vl[q]);
                vg[q] += 64;
            }
            __syncthreads();
            if (j0 > si + 15) continue;

            // S = Q K^T: 16 rows x 64 cols per wave
            f32x4 sc[4];
            for (int ct = 0; ct < 4; ct++) sc[ct] = zero4;
            for (int kt = 0; kt < 4; kt++)
                for (int ct = 0; ct < 4; ct++) {
                    bf16x8 bfr = *(const bf16x8*)&k_s[kt * 2048 + (ct * 16 + ln) * 32 + quad * 8];
                    sc[ct] = __builtin_amdgcn_mfma_f32_16x16x32_bf16(qf[kt], bfr, sc[ct], 0, 0, 0);
                }

            bool full = (j0 + 63 <= si);
            float s2[4][4];
            float aj0 = slope2 * (float)(j0 + ln);
            for (int ct = 0; ct < 4; ct++) {
                float ajv = aj0 + slope2 * (float)(16 * ct);
                int j = j0 + ct * 16 + ln;
                for (int r = 0; r < 4; r++) {
                    float v = fmaf(sc[ct][r], scl, ajv);
                    if (!full) {
                        int i = si + quad * 4 + r;
                        if (j > i) v = -3.0e38f;
                    }
                    s2[ct][r] = v;
                }
            }
            float alpha[4];
            bool any_resc = false;
            for (int r = 0; r < 4; r++) {
                float mr = fmaxf(fmaxf(s2[0][r], s2[1][r]), fmaxf(s2[2][r], s2[3][r]));
                mr = red16_max(mr);
                float mnew = fmaxf(m_i[r], mr);
                alpha[r] = exp2f(m_i[r] - mnew);
                any_resc |= (alpha[r] != 1.0f);
                m_i[r] = mnew;
                for (int ct = 0; ct < 4; ct++) {
                    float p = exp2f(s2[ct][r] - mnew);
                    u16 pb = (u16)(__float_as_uint(p) >> 16);  // trunc; consistent num/denom
                    pw[(quad * 4 + r) * 72 + ct * 16 + ln] = pb;
                }
            }
            if (__any(any_resc)) {
                for (int dt = 0; dt < 8; dt++) {
                    f32x4 o = o_acc[dt];
                    for (int r = 0; r < 4; r++) o[r] *= alpha[r];
                    o_acc[dt] = o;
                }
                for (int r = 0; r < 4; r++) l_acc[r] *= alpha[r];
            }
            asm volatile("s_waitcnt lgkmcnt(0)" ::: "memory");
            for (int ks = 0; ks < 2; ks++) {
                bf16x8 pa = *(const bf16x8*)&pw[ln * 72 + ks * 32 + quad * 8];
                l_acc = __builtin_amdgcn_mfma_f32_16x16x32_bf16(pa, ones, l_acc, 0, 0, 0);
                for (int dt = 0; dt < 8; dt++) {
                    bf16x8 vf = *(const bf16x8*)&vt_s[ks * 4096 + (dt * 16 + ln) * 32 + quad * 8];
                    o_acc[dt] = __builtin_amdgcn_mfma_f32_16x16x32_bf16(pa, vf, o_acc[dt], 0, 0, 0);
                }
            }
        }

        // epilogue: normalize (rcp), SiLU(p) gate (exp2+rcp), store bf16
        float rinv[4];
        for (int r = 0; r < 4; r++) rinv[r] = __builtin_amdgcn_rcpf(l_acc[r]);
        for (int dt = 0; dt < 8; dt++)
            for (int r = 0; r < 4; r++) {
                int i = si + quad * 4 + r;
                int dcol = dt * 16 + ln;
                float o = o_acc[dt][r] * rinv[r];
                float pv = bf2f(qkvp[(tokb + i) * 8192 + 6144 + h * DH + dcol]);
                float gate = pv * __builtin_amdgcn_rcpf(1.0f + exp2f(-pv * LOG2E));
                ag2[(tokb + i) * 2048 + h * DH + dcol] = f2bf(gate * o);
            }
    }
}

extern "C" void kernel_launch(void* const* d_in, const int* in_sizes, int n_in,
                              void* d_out, int out_size, void* d_ws, size_t ws_size,
                              hipStream_t stream) {
    const float* x       = (const float*)d_in[0];
    const float* ln1_g   = (const float*)d_in[1];
    const float* ln1_b   = (const float*)d_in[2];
    const float* ln2_g   = (const float*)d_in[3];
    const float* ln2_b   = (const float*)d_in[4];
    const float* w_in    = (const float*)d_in[5];
    const float* w_out   = (const float*)d_in[6];
    const float* smear_f = (const float*)d_in[7];
    const float* logsc   = (const float*)d_in[8];
    float* out = (float*)d_out;
    char* ws = (char*)d_ws;

    // ws layout (bytes)
    u16* w_inT   = (u16*)(ws + 0);                       // 16 MB  [8192,1024]
    u16* w_outT  = (u16*)(ws + (size_t)16777216);        //  4 MB  [1024,2048]
    u16* lnA     = (u16*)(ws + (size_t)20971520);        //  8 MB  [4096,1024]
    u16* qkvp    = (u16*)(ws + (size_t)29360128);        // 64 MB  [4096,8192]
    u16* k_sm    = (u16*)(ws + (size_t)96468992);        // 16 MB  [bh][l][128]
    u16* ag2     = (u16*)(ws + (size_t)113246208);       // 16 MB  [4096,2048]
    float* out_pre = (float*)(ws + (size_t)96468992);    // alias k_sm (dead after attn)
    u16* v_t     = (u16*)(ws + 0);                       // alias w_inT (dead after gemm1)

    dim3 b32x8(32, 8);
    conv_transpose<<<dim3(8192 / 32, 1024 / 32), b32x8, 0, stream>>>(w_in, w_inT, 1024, 8192);
    conv_transpose<<<dim3(1024 / 32, 2048 / 32), b32x8, 0, stream>>>(w_out, w_outT, 2048, 1024);
    ln_fwd<<<NTOK, 256, 0, stream>>>(x, ln1_g, ln1_b, (void*)lnA, 1);
    gemm_bt<u16><<<dim3(8192 / 128, 4096 / 128), 256, 0, stream>>>(lnA, w_inT, qkvp, NTOK, 8192, 1024);
    smear_kernel<<<4096, 256, 0, stream>>>(qkvp, smear_f, k_sm);
    vT_kernel<<<dim3(L_SEQ / 32, DH / 32, 32), b32x8, 0, stream>>>(qkvp, v_t);
    attn_kernel<<<dim3(16, 32), 256, 0, stream>>>(qkvp, k_sm, v_t, ag2, logsc);
    gemm_bt<float><<<dim3(1024 / 128, 4096 / 128), 256, 0, stream>>>(ag2, w_outT, out_pre, NTOK, 1024, 2048);
    ln_fwd<<<NTOK, 256, 0, stream>>>(out_pre, ln2_g, ln2_b, (void*)out, 0);
}